// Round 8
// baseline (171.328 us; speedup 1.0000x reference)
//
#include <hip/hip_runtime.h>
#include <stdint.h>

typedef unsigned int u32;
typedef unsigned long long u64;

#define TOPK 100
#define CAP 4096
#define NB 512
#define BINBASE 32000u     // (0x3E800000 >> 15): bin 0 == 0.25f
#define KA_BLOCKS 788      // task = (2px, anchor); L0 153600, L1 38400, L2 9600
#define NCOLLECT 788
#define KBT_BLOCKS 793     // 5 tail blocks (0-4) + 788 collect blocks (5-792)

__device__ const float ANC[3][3][2] = {
  {{12.f,16.f},{19.f,36.f},{40.f,28.f}},
  {{36.f,75.f},{76.f,55.f},{72.f,146.f}},
  {{142.f,110.f},{192.f,243.f},{459.f,401.f}}
};

__device__ __forceinline__ float sigmoidf_(float x) {
  if (x >= 0.f) return 1.f / (1.f + expf(-x));
  float e = expf(x);
  return e / (1.f + e);
}

__device__ __forceinline__ float fcomp2(const float2& v, int q) {
  return q ? v.y : v.x;
}

// ---------------- kA: scan -> amax per (anchor,2px) + per-level histogram of anchor maxima ----------------
__global__ __launch_bounds__(256) void kA_scan(
    const float* __restrict__ obj0, const float* __restrict__ cls0,
    const float* __restrict__ obj1, const float* __restrict__ cls1,
    const float* __restrict__ obj2, const float* __restrict__ cls2,
    u32* __restrict__ hist, float* __restrict__ amax)
{
  __shared__ u32 h[NB];
  int tid = threadIdx.x;
  h[tid] = 0; h[tid + 256] = 0;
  __syncthreads();

  int b = blockIdx.x;
  const float *obj, *cls; int P, L, abase; u32 task;
  if (b < 600)      { L=0; obj=obj0; cls=cls0; P=102400; abase=0;      task=(u32)(b*256+tid); }
  else if (b < 750) { L=1; obj=obj1; cls=cls1; P=25600;  abase=307200; task=(u32)((b-600)*256+tid); }
  else              { L=2; obj=obj2; cls=cls2; P=6400;   abase=384000; task=(u32)((b-750)*256+tid); }
  int tpa = P >> 1;
  bool valid = task < (u32)(3*tpa);

  if (valid) {
    int a = (int)(task / (u32)tpa), rem = (int)(task % (u32)tpa);
    int p0 = rem * 2;
    float2 o2 = *(const float2*)(obj + a*P + p0);
    const float* cp = cls + (size_t)(a*20)*P + p0;
    float2 cv[20];
    #pragma unroll
    for (int k = 0; k < 20; ++k) cv[k] = *(const float2*)(cp + (size_t)k*P);
    float2 cm = cv[0];
    #pragma unroll
    for (int k = 1; k < 20; ++k) {
      cm.x = fmaxf(cm.x, cv[k].x); cm.y = fmaxf(cm.y, cv[k].y);
    }
    // sigmoid monotone: max_k sig(o)*sig(c_k) == sig(o)*sig(max_k c_k)
    float2 am2;
    am2.x = sigmoidf_(o2.x) * sigmoidf_(cm.x);
    am2.y = sigmoidf_(o2.y) * sigmoidf_(cm.y);
    *(float2*)(amax + abase + a*P + p0) = am2;
    #pragma unroll
    for (int q = 0; q < 2; ++q) {
      u32 bt = __float_as_uint(fcomp2(am2, q));
      if (bt >= (BINBASE << 15)) {
        u32 bin = (bt >> 15) - BINBASE;
        if (bin < NB) atomicAdd(&h[bin], 1u);
      }
    }
  }
  __syncthreads();
  if (h[tid])       atomicAdd(&hist[L*NB + tid],       h[tid]);
  if (h[tid + 256]) atomicAdd(&hist[L*NB + tid + 256], h[tid + 256]);
}

// ---------------- kBT2: collect (blocks 5-792, 256t) + tail (blocks 0-4) in ONE dispatch ----------------
// Collect blocks: threshold scan + amax-gated collect (agent cand stores) + release done++.
// Tail blocks (launched first, co-resident): spin done==788 (acquire), then redundant
// select+decode+merge; block role r computes matrix chunk ((r==0)?4:r-1); roles 1-4
// publish via matg+bar; role 0 gathers + greedy + output. Collect never waits -> no deadlock.
__global__ __launch_bounds__(256) void kBT2_collect_nms(
    const float* __restrict__ obj0, const float* __restrict__ cls0,
    const float* __restrict__ obj1, const float* __restrict__ cls1,
    const float* __restrict__ obj2, const float* __restrict__ cls2,
    const float* __restrict__ reg0, const float* __restrict__ reg1, const float* __restrict__ reg2,
    const float* __restrict__ amax, const u32* __restrict__ hist,
    u32* __restrict__ cnt, u64* __restrict__ cand,
    u32* __restrict__ done, u32* __restrict__ bar, u64* __restrict__ matg,
    float* __restrict__ out)
{
  extern __shared__ uint8_t smem[];
  int tid = threadIdx.x;
  int b = blockIdx.x;

  if (b >= 5) {
    // ================= collect path (identical logic to r7 kB) =================
    u32* s = (u32*)smem;                 // [512]
    u32* sThrP = (u32*)(smem + 2048);
    int cb = b - 5;
    const float *obj, *cls; int P, L, abase; u32 task;
    if (cb < 600)      { L=0; obj=obj0; cls=cls0; P=102400; abase=0;      task=(u32)(cb*256+tid); }
    else if (cb < 750) { L=1; obj=obj1; cls=cls1; P=25600;  abase=307200; task=(u32)((cb-600)*256+tid); }
    else               { L=2; obj=obj2; cls=cls2; P=6400;   abase=384000; task=(u32)((cb-750)*256+tid); }
    int tpa = P >> 1;
    bool valid = task < (u32)(3*tpa);

    s[tid] = hist[L*NB + tid]; s[tid + 256] = hist[L*NB + tid + 256];
    __syncthreads();
    for (int off = 1; off < NB; off <<= 1) {
      u32 v0 = s[tid]       + ((tid + off < NB)       ? s[tid + off]       : 0u);
      u32 v1 = s[tid + 256] + ((tid + 256 + off < NB) ? s[tid + 256 + off] : 0u);
      __syncthreads();
      s[tid] = v0; s[tid + 256] = v1;
      __syncthreads();
    }
    if (tid == 0 && s[0] < TOPK) *sThrP = BINBASE << 15;   // fallback
    {
      int i0 = tid, i1 = tid + 256;
      u32 a0 = s[i0], n0 = (i0 + 1 < NB) ? s[i0 + 1] : 0u;
      if (a0 >= TOPK && n0 < TOPK) *sThrP = (BINBASE + (u32)i0) << 15;
      u32 a1 = s[i1], n1 = (i1 + 1 < NB) ? s[i1 + 1] : 0u;
      if (a1 >= TOPK && n1 < TOPK) *sThrP = (BINBASE + (u32)i1) << 15;
    }
    __syncthreads();
    u32 thr = *sThrP;

    if (valid) {
      int a = (int)(task / (u32)tpa), rem = (int)(task % (u32)tpa);
      int p0 = rem * 2;
      float2 am2 = *(const float2*)(amax + abase + a*P + p0);
      bool any = (__float_as_uint(am2.x) >= thr) | (__float_as_uint(am2.y) >= thr);
      if (any) {
        float2 o2 = *(const float2*)(obj + a*P + p0);
        const float* cp = cls + (size_t)(a*20)*P + p0;
        float2 cv[20];
        #pragma unroll
        for (int k = 0; k < 20; ++k) cv[k] = *(const float2*)(cp + (size_t)k*P);
        #pragma unroll
        for (int q = 0; q < 2; ++q) {
          if (__float_as_uint(fcomp2(am2, q)) >= thr) {
            float so = sigmoidf_(fcomp2(o2, q));
            int p = p0 + q;
            #pragma unroll
            for (int k = 0; k < 20; ++k) {
              float sc = so * sigmoidf_(fcomp2(cv[k], q));
              u32 bits = __float_as_uint(sc);
              if (bits >= thr) {
                u32 pos = atomicAdd(&cnt[L], 1u);
                u32 idx = (u32)(p*60 + a*20 + k);
                if (pos < CAP)
                  __hip_atomic_store(&cand[L*CAP + pos],
                                     ((u64)bits << 32) | (u64)(0x00FFFFFFu - idx),
                                     __ATOMIC_RELAXED, __HIP_MEMORY_SCOPE_AGENT);
              }
            }
          }
        }
      }
    }
    __syncthreads();   // drains all waves' stores before the release increment
    if (tid == 0)
      __hip_atomic_fetch_add(done, 1u, __ATOMIC_RELEASE, __HIP_MEMORY_SCOPE_AGENT);
    return;
  }

  // ================= tail path (blocks 0-4, 256 threads) =================
  u64*    mat   = (u64*)(smem);             // [1500] — Phase A key cache, then matrix rows
  float4* ibox4 = (float4*)(smem + 12000);  // [300]
  float2* iml2  = (float2*)(smem + 16800);  // [300] (area, label)
  float*  x1s   = (float*)(smem + 19200);
  float*  y1s   = (float*)(smem + 20400);
  float*  x2s   = (float*)(smem + 21600);
  float*  y2s   = (float*)(smem + 22800);
  float*  sc2   = (float*)(smem + 24000);
  int*    lb2   = (int*)(smem + 25200);
  int*    vd2   = (int*)(smem + 26400);
  u64*    rowAny= (u64*)(smem + 27600);     // [5]
  u64*    km    = (u64*)(smem + 27648);     // [5]
  float*  ars   = (float*)(smem + 27696);   // [300]
  u64*    sel   = (u64*)(smem + 28896);     // [300] -> 31296

  int role = b;   // 0..4; role 0 = gatherer (chunk 4 in LDS)

  // wait for all collect blocks (5 spinner waves total grid-wide — cheap regime)
  if (tid == 0) {
    while (__hip_atomic_load(done, __ATOMIC_ACQUIRE, __HIP_MEMORY_SCOPE_AGENT) < (u32)NCOLLECT)
      __builtin_amdgcn_s_sleep(2);
  }
  __syncthreads();

  for (int t0 = tid; t0 < 300; t0 += 256) sel[t0] = 0ull;
  __syncthreads();

  // ---- Phase A: per-level exact top-100, 3 levels concurrent (groups 96/96/64) ----
  {
    int gL    = (tid >= 192) ? 2 : (tid >= 96) ? 1 : 0;
    int gbase = (gL == 2) ? 192 : (gL == 1) ? 96 : 0;
    int lt    = tid - gbase;
    int gsz   = (gL == 2) ? 64 : 96;

    u32 n = __hip_atomic_load(&cnt[gL], __ATOMIC_RELAXED, __HIP_MEMORY_SCOPE_AGENT);
    if (n > CAP) n = CAP;
    bool useLds = (n <= 496);                  // 3*500 u64 fits in mat[1500]
    u64* kc = mat + gL*500;
    const u64* cb2 = cand + gL*CAP;
    u32 n4 = (n + 3u) & ~3u;

    if (useLds) {
      for (u32 j = (u32)lt; j < n; j += gsz)
        kc[j] = __hip_atomic_load(&cb2[j], __ATOMIC_RELAXED, __HIP_MEMORY_SCOPE_AGENT);
      if (lt < 4 && n + (u32)lt < n4) kc[n + lt] = 0ull;   // pad (n4 <= 500)
    }
    __syncthreads();   // uniform barrier (outside divergent ifs)

    if (useLds) {
      for (u32 j = (u32)lt; j < n; j += gsz) {
        u64 kk = kc[j]; int r = 0;
        for (u32 t = 0; t < n4; t += 4) {
          u64 k0 = kc[t], k1 = kc[t+1], k2 = kc[t+2], k3 = kc[t+3];
          r += (k0 > kk) ? 1 : 0; r += (k1 > kk) ? 1 : 0;
          r += (k2 > kk) ? 1 : 0; r += (k3 > kk) ? 1 : 0;
        }
        if (r < TOPK) sel[gL*TOPK + r] = kk;
      }
    } else {
      for (u32 j = (u32)lt; j < n; j += gsz) {
        u64 kk = __hip_atomic_load(&cb2[j], __ATOMIC_RELAXED, __HIP_MEMORY_SCOPE_AGENT);
        int r = 0;
        for (u32 t = 0; t < n; ++t)
          r += (__hip_atomic_load(&cb2[t], __ATOMIC_RELAXED, __HIP_MEMORY_SCOPE_AGENT) > kk) ? 1 : 0;
        if (r < TOPK) sel[gL*TOPK + r] = kk;
      }
    }
  }
  __syncthreads();

  // ---- Phase BC (fused): decode in registers + 3-way merge rank + direct sorted write ----
  for (int t0 = tid; t0 < 300; t0 += 256) {
    int Lm = t0 / TOPK, rr = t0 % TOPK;
    u64 key = sel[t0];

    const float* reg; int Pq, W, stride;
    if (Lm == 0)      { reg = reg0; Pq = 102400; W = 320; stride = 8; }
    else if (Lm == 1) { reg = reg1; Pq = 25600;  W = 160; stride = 16; }
    else              { reg = reg2; Pq = 6400;   W = 80;  stride = 32; }
    float x1, y1, x2, y2, score; int lab, vld;
    if (key == 0) {
      x1 = y1 = x2 = y2 = 0.f; score = 0.f; lab = 0; vld = 0;
    } else {
      score = __uint_as_float((u32)(key >> 32));
      u32 i = 0x00FFFFFFu - (u32)(key & 0xFFFFFFFFull);
      int c = (int)(i % 60u), p = (int)(i / 60u);
      int aa = c / 20, k = c % 20;
      int x = p % W, y = p / W;
      float tx = reg[(aa*4+0)*Pq + p], ty = reg[(aa*4+1)*Pq + p];
      float tw = reg[(aa*4+2)*Pq + p], th = reg[(aa*4+3)*Pq + p];
      float cx = (sigmoidf_(tx)*3.f - 1.5f + (float)x + 0.5f) * (float)stride;
      float cy = (sigmoidf_(ty)*3.f - 1.5f + (float)y + 0.5f) * (float)stride;
      float bw = expf(tw) * ANC[Lm][aa][0];
      float bh = expf(th) * ANC[Lm][aa][1];
      lab = k; vld = (score > 0.01f) ? 1 : 0;
      x1 = cx - 0.5f*bw; y1 = cy - 0.5f*bh;
      x2 = cx + 0.5f*bw; y2 = cy + 0.5f*bh;
    }

    int rank = rr;
    #pragma unroll
    for (int Lo = 0; Lo < 3; ++Lo) {
      if (Lo == Lm) continue;
      const u64* arr = sel + Lo*TOPK;
      bool ge = (Lo < Lm);     // earlier level wins ties (stable concat order)
      int lo = 0;
      #pragma unroll
      for (int st = 64; st > 0; st >>= 1) {
        int nxt = lo + st;
        if (nxt <= TOPK) {
          u64 v = arr[nxt - 1];
          bool pred = ge ? (v >= key) : (v > key);
          if (pred) lo = nxt;
        }
      }
      rank += lo;
    }

    float ar = (x2 - x1) * (y2 - y1);
    ibox4[rank] = make_float4(x1, y1, x2, y2);
    iml2[rank]  = make_float2(ar, (float)lab);
    x1s[rank] = x1; y1s[rank] = y1; x2s[rank] = x2; y2s[rank] = y2; ars[rank] = ar;
    sc2[rank] = score; lb2[rank] = lab; vd2[rank] = vld;
  }
  __syncthreads();

  // ---- Phase D: this block's matrix j-chunk, 4 waves striping i ----
  {
    int w = (role == 0) ? 4 : (role - 1);
    int wave = tid >> 6, lane = tid & 63;
    int j = w*64 + lane;
    bool jv = j < 300;
    float jx1=0.f, jy1=0.f, jx2=0.f, jy2=0.f, jar=0.f; float jlb=-1.f;
    if (jv) { jx1=x1s[j]; jy1=y1s[j]; jx2=x2s[j]; jy2=y2s[j]; jar=ars[j]; jlb=(float)lb2[j]; }
    int ilim = (w+1)*64; if (ilim > 300) ilim = 300;
    for (int i = wave; i < ilim; i += 4) {
      float4 B = ibox4[i];          // b128 broadcast
      float2 M = iml2[i];           // b64 broadcast (area, label)
      float xx1 = fmaxf(B.x, jx1), yy1 = fmaxf(B.y, jy1);
      float xx2 = fminf(B.z, jx2), yy2 = fminf(B.w, jy2);
      float inter = fmaxf(1e-10f, xx2-xx1) * fmaxf(1e-10f, yy2-yy1);
      float iou = inter / (M.x + jar - inter);
      bool pred = jv && (iou > 0.5f) && (M.y == jlb);
      u64 m = __ballot(pred);
      if (lane == 0) {
        if (role == 0) mat[i*5 + 4] = m;   // chunk 4 stays in LDS
        else __hip_atomic_store(&matg[i*5 + w], m, __ATOMIC_RELAXED, __HIP_MEMORY_SCOPE_AGENT);
      }
    }
  }
  __syncthreads();   // drains stores before publish

  if (role != 0) {
    if (tid == 0)
      __hip_atomic_fetch_add(bar, 1u, __ATOMIC_RELEASE, __HIP_MEMORY_SCOPE_AGENT);
    return;
  }

  // ---- role 0: wait for chunks 0-3 (single spinner), gather to LDS ----
  if (tid == 0) {
    while (__hip_atomic_load(bar, __ATOMIC_ACQUIRE, __HIP_MEMORY_SCOPE_AGENT) < 4u)
      __builtin_amdgcn_s_sleep(1);
  }
  __syncthreads();
  for (int idx = tid; idx < 1200; idx += 256) {
    int w2 = idx / 300, i = idx % 300;
    if (i < (w2+1)*64)
      mat[i*5 + w2] = __hip_atomic_load(&matg[i*5 + w2], __ATOMIC_RELAXED, __HIP_MEMORY_SCOPE_AGENT);
  }
  __syncthreads();

  // ---- Phase D2 (two passes on 256 threads): rowAny[c] bit t = row suppresses above ----
  {
    // pass 1: rows 0-255 (chunks 0-3)
    bool flag = false;
    {
      int row = tid, c = row >> 6, bq = row & 63;
      u64 acc = mat[row*5 + c] & ((bq == 63) ? 0ull : (~0ull << (bq + 1)));
      for (int w = c + 1; w < 5; ++w) acc |= mat[row*5 + w];
      flag = (acc != 0ull);
    }
    u64 bal = __ballot(flag);
    if ((tid & 63) == 0) rowAny[tid >> 6] = bal;
    // pass 2: rows 256-299 (chunk 4), wave 0 covers them
    bool flag2 = false;
    {
      int row = 256 + tid;
      if (row < 300) {
        int bq = row & 63;  // == tid (<44)
        u64 acc = mat[row*5 + 4] & ((bq == 63) ? 0ull : (~0ull << (bq + 1)));
        flag2 = (acc != 0ull);
      }
    }
    u64 bal2 = __ballot(flag2);
    if (tid == 0) rowAny[4] = bal2;
  }
  __syncthreads();

  // ---- Phase E: greedy scan; common path register-only ----
  if (tid < 64) {
    int lane = tid;
    u64 vm[5];
    #pragma unroll
    for (int c = 0; c < 5; ++c) {
      int j = c*64 + lane;
      vm[c] = __ballot((j < 300) && (vd2[j] != 0));
    }
    u64 ra[5];
    #pragma unroll
    for (int c = 0; c < 5; ++c) ra[c] = rowAny[c];
    u64 S[5] = {0,0,0,0,0};
    #pragma unroll
    for (int c = 0; c < 5; ++c) {
      u64 kbits = 0;
      int lim = (c == 4) ? 44 : 64;
      for (int t = 0; t < lim; ++t) {
        u64 kept = ((~(S[c] >> t)) & (vm[c] >> t)) & 1ull;
        kbits |= kept << t;
        if (kept & ((ra[c] >> t) & 1ull)) {
          int i = c*64 + t;
          #pragma unroll
          for (int w = 0; w < 5; ++w)
            if (w >= c) S[w] |= mat[i*5 + w];
        }
      }
      if (lane == 0) km[c] = kbits;
    }
  }
  __syncthreads();

  // ---- Phase F: output ----
  for (int t0 = tid; t0 < 300; t0 += 256) {
    float kf = (float)((km[t0 >> 6] >> (t0 & 63)) & 1ull);
    float4 bq = ibox4[t0];
    out[t0*4+0] = bq.x; out[t0*4+1] = bq.y;
    out[t0*4+2] = bq.z; out[t0*4+3] = bq.w;
    out[1200+t0] = sc2[t0] * kf;
    out[1500+t0] = (float)lb2[t0];
    out[1800+t0] = kf;
  }
}

extern "C" void kernel_launch(void* const* d_in, const int* in_sizes, int n_in,
                              void* d_out, int out_size, void* d_ws, size_t ws_size,
                              hipStream_t stream) {
  const float* obj0 = (const float*)d_in[0];
  const float* cls0 = (const float*)d_in[1];
  const float* reg0 = (const float*)d_in[2];
  const float* obj1 = (const float*)d_in[3];
  const float* cls1 = (const float*)d_in[4];
  const float* reg1 = (const float*)d_in[5];
  const float* obj2 = (const float*)d_in[6];
  const float* cls2 = (const float*)d_in[7];
  const float* reg2 = (const float*)d_in[8];
  float* out = (float*)d_out;

  uint8_t* ws = (uint8_t*)d_ws;
  u32*   hist = (u32*)(ws + 0);          // 3*512*4 = 6144
  u32*   cnt  = (u32*)(ws + 6144);       // 12 -> 6156
  u32*   bar  = (u32*)(ws + 6156);       // 4  -> 6160
  u32*   done = (u32*)(ws + 6160);       // 4  -> 6164
  u64*   cand = (u64*)(ws + 8192);       // 3*4096*8 -> 106496
  u64*   matg = (u64*)(ws + 106496);     // 1500*8 = 12000 -> 118496
  float* amax = (float*)(ws + 118496);   // 403200*4 -> 1731296

  (void)hipMemsetAsync(ws, 0, 6164, stream);   // zero hist + cnt + bar + done

  kA_scan<<<dim3(KA_BLOCKS), dim3(256), 0, stream>>>(
      obj0, cls0, obj1, cls1, obj2, cls2, hist, amax);
  kBT2_collect_nms<<<dim3(KBT_BLOCKS), dim3(256), 31296, stream>>>(
      obj0, cls0, obj1, cls1, obj2, cls2, reg0, reg1, reg2,
      amax, hist, cnt, cand, done, bar, matg, out);
}

// Round 9
// 132.481 us; speedup vs baseline: 1.2932x; 1.2932x over previous
//
#include <hip/hip_runtime.h>
#include <stdint.h>

typedef unsigned int u32;
typedef unsigned long long u64;

#define TOPK 100
#define CAP 4096
#define NB 512
#define BINBASE 32000u     // (0x3E800000 >> 15): bin 0 == 0.25f
#define KAB_BLOCKS 788     // task = (2px, anchor); L0 153600, L1 38400, L2 9600

__device__ const float ANC[3][3][2] = {
  {{12.f,16.f},{19.f,36.f},{40.f,28.f}},
  {{36.f,75.f},{76.f,55.f},{72.f,146.f}},
  {{142.f,110.f},{192.f,243.f},{459.f,401.f}}
};

__device__ __forceinline__ float sigmoidf_(float x) {
  if (x >= 0.f) return 1.f / (1.f + expf(-x));
  float e = expf(x);
  return e / (1.f + e);
}

__device__ __forceinline__ float fcomp2(const float2& v, int q) {
  return q ? v.y : v.x;
}

// ---------------- kA: scan -> amax per (anchor,2px) + per-level histogram of anchor maxima ----------------
__global__ __launch_bounds__(256) void kA_scan(
    const float* __restrict__ obj0, const float* __restrict__ cls0,
    const float* __restrict__ obj1, const float* __restrict__ cls1,
    const float* __restrict__ obj2, const float* __restrict__ cls2,
    u32* __restrict__ hist, float* __restrict__ amax)
{
  __shared__ u32 h[NB];
  int tid = threadIdx.x;
  h[tid] = 0; h[tid + 256] = 0;
  __syncthreads();

  int b = blockIdx.x;
  const float *obj, *cls; int P, L, abase; u32 task;
  if (b < 600)      { L=0; obj=obj0; cls=cls0; P=102400; abase=0;      task=(u32)(b*256+tid); }
  else if (b < 750) { L=1; obj=obj1; cls=cls1; P=25600;  abase=307200; task=(u32)((b-600)*256+tid); }
  else              { L=2; obj=obj2; cls=cls2; P=6400;   abase=384000; task=(u32)((b-750)*256+tid); }
  int tpa = P >> 1;
  bool valid = task < (u32)(3*tpa);

  if (valid) {
    int a = (int)(task / (u32)tpa), rem = (int)(task % (u32)tpa);
    int p0 = rem * 2;
    float2 o2 = *(const float2*)(obj + a*P + p0);
    const float* cp = cls + (size_t)(a*20)*P + p0;
    float2 cv[20];
    #pragma unroll
    for (int k = 0; k < 20; ++k) cv[k] = *(const float2*)(cp + (size_t)k*P);
    float2 cm = cv[0];
    #pragma unroll
    for (int k = 1; k < 20; ++k) {
      cm.x = fmaxf(cm.x, cv[k].x); cm.y = fmaxf(cm.y, cv[k].y);
    }
    // sigmoid monotone: max_k sig(o)*sig(c_k) == sig(o)*sig(max_k c_k)
    float2 am2;
    am2.x = sigmoidf_(o2.x) * sigmoidf_(cm.x);
    am2.y = sigmoidf_(o2.y) * sigmoidf_(cm.y);
    *(float2*)(amax + abase + a*P + p0) = am2;
    #pragma unroll
    for (int q = 0; q < 2; ++q) {
      u32 bt = __float_as_uint(fcomp2(am2, q));
      if (bt >= (BINBASE << 15)) {
        u32 bin = (bt >> 15) - BINBASE;
        if (bin < NB) atomicAdd(&h[bin], 1u);
      }
    }
  }
  __syncthreads();
  if (h[tid])       atomicAdd(&hist[L*NB + tid],       h[tid]);
  if (h[tid + 256]) atomicAdd(&hist[L*NB + tid + 256], h[tid + 256]);
}

// ---------------- kB: per-block threshold (suffix scan) + amax-gated collect ----------------
__global__ __launch_bounds__(256) void kB_collect(
    const float* __restrict__ obj0, const float* __restrict__ cls0,
    const float* __restrict__ obj1, const float* __restrict__ cls1,
    const float* __restrict__ obj2, const float* __restrict__ cls2,
    const float* __restrict__ amax, const u32* __restrict__ hist,
    u32* __restrict__ cnt, u64* __restrict__ cand)
{
  __shared__ u32 s[NB];
  __shared__ u32 sThr;
  int tid = threadIdx.x;
  int b = blockIdx.x;
  const float *obj, *cls; int P, L, abase; u32 task;
  if (b < 600)      { L=0; obj=obj0; cls=cls0; P=102400; abase=0;      task=(u32)(b*256+tid); }
  else if (b < 750) { L=1; obj=obj1; cls=cls1; P=25600;  abase=307200; task=(u32)((b-600)*256+tid); }
  else              { L=2; obj=obj2; cls=cls2; P=6400;   abase=384000; task=(u32)((b-750)*256+tid); }
  int tpa = P >> 1;
  bool valid = task < (u32)(3*tpa);

  s[tid] = hist[L*NB + tid]; s[tid + 256] = hist[L*NB + tid + 256];
  __syncthreads();
  for (int off = 1; off < NB; off <<= 1) {
    u32 v0 = s[tid]       + ((tid + off < NB)       ? s[tid + off]       : 0u);
    u32 v1 = s[tid + 256] + ((tid + 256 + off < NB) ? s[tid + 256 + off] : 0u);
    __syncthreads();
    s[tid] = v0; s[tid + 256] = v1;
    __syncthreads();
  }
  if (tid == 0 && s[0] < TOPK) sThr = BINBASE << 15;   // fallback
  {
    int i0 = tid, i1 = tid + 256;
    u32 a0 = s[i0], n0 = (i0 + 1 < NB) ? s[i0 + 1] : 0u;
    if (a0 >= TOPK && n0 < TOPK) sThr = (BINBASE + (u32)i0) << 15;
    u32 a1 = s[i1], n1 = (i1 + 1 < NB) ? s[i1 + 1] : 0u;
    if (a1 >= TOPK && n1 < TOPK) sThr = (BINBASE + (u32)i1) << 15;
  }
  __syncthreads();
  u32 thr = sThr;

  if (valid) {
    int a = (int)(task / (u32)tpa), rem = (int)(task % (u32)tpa);
    int p0 = rem * 2;
    float2 am2 = *(const float2*)(amax + abase + a*P + p0);
    bool any = (__float_as_uint(am2.x) >= thr) | (__float_as_uint(am2.y) >= thr);
    if (any) {
      // rare path (~hundreds of threads grid-wide); cache-hot reloads
      float2 o2 = *(const float2*)(obj + a*P + p0);
      const float* cp = cls + (size_t)(a*20)*P + p0;
      float2 cv[20];
      #pragma unroll
      for (int k = 0; k < 20; ++k) cv[k] = *(const float2*)(cp + (size_t)k*P);
      #pragma unroll
      for (int q = 0; q < 2; ++q) {
        if (__float_as_uint(fcomp2(am2, q)) >= thr) {
          float so = sigmoidf_(fcomp2(o2, q));
          int p = p0 + q;
          #pragma unroll
          for (int k = 0; k < 20; ++k) {
            float sc = so * sigmoidf_(fcomp2(cv[k], q));
            u32 bits = __float_as_uint(sc);
            if (bits >= thr) {
              u32 pos = atomicAdd(&cnt[L], 1u);
              u32 idx = (u32)(p*60 + a*20 + k);
              if (pos < CAP) cand[L*CAP + pos] = ((u64)bits << 32) | (u64)(0x00FFFFFFu - idx);
            }
          }
        }
      }
    }
  }
}

// ---------------- kT: 5-block tail. All blocks: select + fused decode/merge (redundant).
// Block b computes matrix j-chunk ((b==0)?4:b-1); blocks 1-4 publish via agent stores
// + release counter; block 0 (single spinner) gathers + greedy + output. ----------------
__global__ __launch_bounds__(1024) void kT_select_nms(
    const float* __restrict__ reg0, const float* __restrict__ reg1, const float* __restrict__ reg2,
    const u64* __restrict__ cand, const u32* __restrict__ cnt,
    u64* __restrict__ matg, u32* __restrict__ bar,
    float* __restrict__ out)
{
  extern __shared__ uint8_t smem[];
  u64*    mat   = (u64*)(smem);             // [1500] 12000 B — Phase A key cache, then matrix rows
  float4* ibox4 = (float4*)(smem + 12000);  // [300] sorted boxes (packed) -> 16800
  float2* iml2  = (float2*)(smem + 16800);  // [300] (area, label) -> 19200
  float*  x1s   = (float*)(smem + 19200);   // sorted SoA (j-side)
  float*  y1s   = (float*)(smem + 20400);
  float*  x2s   = (float*)(smem + 21600);
  float*  y2s   = (float*)(smem + 22800);
  float*  sc2   = (float*)(smem + 24000);
  int*    lb2   = (int*)(smem + 25200);
  int*    vd2   = (int*)(smem + 26400);
  u64*    rowAny= (u64*)(smem + 27600);     // [5]
  u64*    km    = (u64*)(smem + 27648);     // [5]
  float*  ars   = (float*)(smem + 27696);   // [300] -> 28896
  u64*    sel   = (u64*)(smem + 28896);     // [300] -> 31296

  int tid = threadIdx.x;
  int b = blockIdx.x;
  if (tid < 300) sel[tid] = 0ull;
  __syncthreads();

  // ---- Phase A: per-level exact top-100, 3 levels CONCURRENT in wave-aligned groups ----
  {
    int gL    = (tid >= 768) ? 2 : (tid >= 384) ? 1 : 0;
    int gbase = (gL == 2) ? 768 : (gL == 1) ? 384 : 0;
    int lt    = tid - gbase;
    int gsz   = (gL == 2) ? 256 : 384;

    u32 n = cnt[gL]; if (n > CAP) n = CAP;
    bool useLds = (n <= 496);                  // 3*500 u64 fits in mat[1500]
    u64* kc = mat + gL*500;
    const u64* cb = cand + gL*CAP;
    u32 n4 = (n + 3u) & ~3u;

    if (useLds) {
      for (u32 j = (u32)lt; j < n; j += gsz) kc[j] = cb[j];
      if (lt < 4 && n + (u32)lt < n4) kc[n + lt] = 0ull;   // pad (n4 <= 500)
    }
    __syncthreads();   // uniform barrier

    if (useLds) {
      for (u32 j = (u32)lt; j < n; j += gsz) {
        u64 kk = kc[j]; int r = 0;
        for (u32 t = 0; t < n4; t += 4) {
          u64 k0 = kc[t], k1 = kc[t+1], k2 = kc[t+2], k3 = kc[t+3];
          r += (k0 > kk) ? 1 : 0; r += (k1 > kk) ? 1 : 0;
          r += (k2 > kk) ? 1 : 0; r += (k3 > kk) ? 1 : 0;
        }
        if (r < TOPK) sel[gL*TOPK + r] = kk;
      }
    } else {
      u32 nn = n & ~3u;
      for (u32 j = (u32)lt; j < n; j += gsz) {
        u64 kk = cb[j]; int r = 0;
        for (u32 t = 0; t < nn; t += 4) {
          r += (cb[t]   > kk) ? 1 : 0; r += (cb[t+1] > kk) ? 1 : 0;
          r += (cb[t+2] > kk) ? 1 : 0; r += (cb[t+3] > kk) ? 1 : 0;
        }
        for (u32 t = nn; t < n; ++t) r += (cb[t] > kk) ? 1 : 0;
        if (r < TOPK) sel[gL*TOPK + r] = kk;
      }
    }
  }
  __syncthreads();

  // ---- Phase BC (fused): decode in registers + 3-way merge rank + direct sorted write ----
  if (tid < 300) {
    int Lm = tid / TOPK, rr = tid % TOPK;
    u64 key = sel[tid];

    // decode (registers only)
    const float* reg; int Pq, W, stride;
    if (Lm == 0)      { reg = reg0; Pq = 102400; W = 320; stride = 8; }
    else if (Lm == 1) { reg = reg1; Pq = 25600;  W = 160; stride = 16; }
    else              { reg = reg2; Pq = 6400;   W = 80;  stride = 32; }
    float x1, y1, x2, y2, score; int lab, vld;
    if (key == 0) {
      x1 = y1 = x2 = y2 = 0.f; score = 0.f; lab = 0; vld = 0;
    } else {
      score = __uint_as_float((u32)(key >> 32));
      u32 i = 0x00FFFFFFu - (u32)(key & 0xFFFFFFFFull);
      int c = (int)(i % 60u), p = (int)(i / 60u);
      int aa = c / 20, k = c % 20;
      int x = p % W, y = p / W;
      float tx = reg[(aa*4+0)*Pq + p], ty = reg[(aa*4+1)*Pq + p];
      float tw = reg[(aa*4+2)*Pq + p], th = reg[(aa*4+3)*Pq + p];
      float cx = (sigmoidf_(tx)*3.f - 1.5f + (float)x + 0.5f) * (float)stride;
      float cy = (sigmoidf_(ty)*3.f - 1.5f + (float)y + 0.5f) * (float)stride;
      float bw = expf(tw) * ANC[Lm][aa][0];
      float bh = expf(th) * ANC[Lm][aa][1];
      lab = k; vld = (score > 0.01f) ? 1 : 0;
      x1 = cx - 0.5f*bw; y1 = cy - 0.5f*bh;
      x2 = cx + 0.5f*bw; y2 = cy + 0.5f*bh;
    }

    // merge rank (stable == jnp argsort(-scores) over concat order)
    int rank = rr;
    #pragma unroll
    for (int Lo = 0; Lo < 3; ++Lo) {
      if (Lo == Lm) continue;
      const u64* arr = sel + Lo*TOPK;
      bool ge = (Lo < Lm);     // earlier level wins ties (stable concat order)
      int lo = 0;
      #pragma unroll
      for (int st = 64; st > 0; st >>= 1) {
        int nxt = lo + st;
        if (nxt <= TOPK) {
          u64 v = arr[nxt - 1];
          bool pred = ge ? (v >= key) : (v > key);
          if (pred) lo = nxt;
        }
      }
      rank += lo;
    }

    float ar = (x2 - x1) * (y2 - y1);
    ibox4[rank] = make_float4(x1, y1, x2, y2);
    iml2[rank]  = make_float2(ar, (float)lab);
    x1s[rank] = x1; y1s[rank] = y1; x2s[rank] = x2; y2s[rank] = y2; ars[rank] = ar;
    sc2[rank] = score; lb2[rank] = lab; vd2[rank] = vld;
  }
  __syncthreads();

  // ---- Phase D: this block's matrix j-chunk, 16 waves striping i ----
  {
    int w = (b == 0) ? 4 : (b - 1);
    int wave = tid >> 6, lane = tid & 63;
    int j = w*64 + lane;
    bool jv = j < 300;
    float jx1=0.f, jy1=0.f, jx2=0.f, jy2=0.f, jar=0.f; float jlb=-1.f;
    if (jv) { jx1=x1s[j]; jy1=y1s[j]; jx2=x2s[j]; jy2=y2s[j]; jar=ars[j]; jlb=(float)lb2[j]; }
    int ilim = (w+1)*64; if (ilim > 300) ilim = 300;
    #pragma unroll 2
    for (int i = wave; i < ilim; i += 16) {
      float4 B = ibox4[i];          // b128 broadcast
      float2 M = iml2[i];           // b64 broadcast (area, label)
      float xx1 = fmaxf(B.x, jx1), yy1 = fmaxf(B.y, jy1);
      float xx2 = fminf(B.z, jx2), yy2 = fminf(B.w, jy2);
      float inter = fmaxf(1e-10f, xx2-xx1) * fmaxf(1e-10f, yy2-yy1);
      float iou = inter / (M.x + jar - inter);
      bool pred = jv && (iou > 0.5f) && (M.y == jlb);
      u64 m = __ballot(pred);
      if (lane == 0) {
        if (b == 0) mat[i*5 + 4] = m;   // chunk 4 stays in LDS
        else __hip_atomic_store(&matg[i*5 + w], m, __ATOMIC_RELAXED, __HIP_MEMORY_SCOPE_AGENT);
      }
    }
  }
  __syncthreads();   // drains all waves' stores before publish

  if (b != 0) {
    if (tid == 0)
      __hip_atomic_fetch_add(bar, 1u, __ATOMIC_RELEASE, __HIP_MEMORY_SCOPE_AGENT);
    return;
  }

  // ---- block 0: wait for chunks 0-3 (single spinner), gather to LDS ----
  if (tid == 0) {
    while (__hip_atomic_load(bar, __ATOMIC_ACQUIRE, __HIP_MEMORY_SCOPE_AGENT) < 4u)
      __builtin_amdgcn_s_sleep(1);
  }
  __syncthreads();
  for (int idx = tid; idx < 1200; idx += 1024) {
    int w2 = idx / 300, i = idx % 300;
    if (i < (w2+1)*64)
      mat[i*5 + w2] = __hip_atomic_load(&matg[i*5 + w2], __ATOMIC_RELAXED, __HIP_MEMORY_SCOPE_AGENT);
  }
  __syncthreads();

  // ---- Phase D2: rowAny[c] bit t = row (c*64+t) suppresses anything above it ----
  {
    bool flag = false;
    if (tid < 300) {
      int c = tid >> 6, bq = tid & 63;
      u64 acc = mat[tid*5 + c] & ((bq == 63) ? 0ull : (~0ull << (bq + 1)));
      for (int w = c + 1; w < 5; ++w) acc |= mat[tid*5 + w];
      flag = (acc != 0ull);
    }
    u64 bal = __ballot(flag);
    if ((tid & 63) == 0 && (tid >> 6) < 5) rowAny[tid >> 6] = bal;
  }
  __syncthreads();

  // ---- Phase E: greedy scan via ctz-span skip. S[c] only changes at KEPT rows that
  // appear in ra[c]; between them, kept bits = ~S & vm for the whole span (O(1)).
  // Exactly equivalent to the bit-serial loop, but iterates popcount(ra) times. ----
  if (tid < 64) {
    int lane = tid;
    u64 vm[5];
    #pragma unroll
    for (int c = 0; c < 5; ++c) {
      int j = c*64 + lane;
      vm[c] = __ballot((j < 300) && (vd2[j] != 0));
    }
    u64 ra[5];
    #pragma unroll
    for (int c = 0; c < 5; ++c) ra[c] = rowAny[c];
    u64 S[5] = {0,0,0,0,0};
    #pragma unroll
    for (int c = 0; c < 5; ++c) {
      int lim = (c == 4) ? 44 : 64;
      u64 limmask = (lim == 64) ? ~0ull : ((1ull << lim) - 1ull);
      u64 kbits = 0;
      u64 pending = ra[c] & limmask;
      int t = 0;
      while (t < lim) {
        int nxt = pending ? (int)__builtin_ctzll(pending) : lim;
        if (nxt > t) {
          // span [t, nxt): S[c] constant (no kept suppressor inside)
          u64 hi = (nxt >= 64) ? ~0ull : ((1ull << nxt) - 1ull);
          u64 lo = (1ull << t) - 1ull;          // t <= 63 here
          kbits |= ((~S[c]) & vm[c]) & hi & ~lo;
        }
        if (nxt >= lim) break;
        // suppressor row nxt: evaluate individually
        u64 kept = ((~(S[c] >> nxt)) & (vm[c] >> nxt)) & 1ull;
        kbits |= kept << nxt;
        if (kept) {
          int i = c*64 + nxt;
          #pragma unroll
          for (int w = 0; w < 5; ++w)
            if (w >= c) S[w] |= mat[i*5 + w];
        }
        pending &= pending - 1ull;
        t = nxt + 1;
      }
      kbits &= limmask;
      if (lane == 0) km[c] = kbits;
    }
  }
  __syncthreads();

  // ---- Phase F: output ----
  if (tid < 300) {
    float kf = (float)((km[tid >> 6] >> (tid & 63)) & 1ull);
    float4 bq = ibox4[tid];
    out[tid*4+0] = bq.x; out[tid*4+1] = bq.y;
    out[tid*4+2] = bq.z; out[tid*4+3] = bq.w;
    out[1200+tid] = sc2[tid] * kf;
    out[1500+tid] = (float)lb2[tid];
    out[1800+tid] = kf;
  }
}

extern "C" void kernel_launch(void* const* d_in, const int* in_sizes, int n_in,
                              void* d_out, int out_size, void* d_ws, size_t ws_size,
                              hipStream_t stream) {
  const float* obj0 = (const float*)d_in[0];
  const float* cls0 = (const float*)d_in[1];
  const float* reg0 = (const float*)d_in[2];
  const float* obj1 = (const float*)d_in[3];
  const float* cls1 = (const float*)d_in[4];
  const float* reg1 = (const float*)d_in[5];
  const float* obj2 = (const float*)d_in[6];
  const float* cls2 = (const float*)d_in[7];
  const float* reg2 = (const float*)d_in[8];
  float* out = (float*)d_out;

  uint8_t* ws = (uint8_t*)d_ws;
  u32*   hist = (u32*)(ws + 0);          // 3*512*4 = 6144
  u32*   cnt  = (u32*)(ws + 6144);       // 12 -> 6156
  u32*   bar  = (u32*)(ws + 6156);       // 4  -> 6160
  u64*   cand = (u64*)(ws + 8192);       // 3*4096*8 -> 106496
  u64*   matg = (u64*)(ws + 106496);     // 1500*8 = 12000 -> 118496
  float* amax = (float*)(ws + 118496);   // 403200*4 -> 1731296

  (void)hipMemsetAsync(ws, 0, 6160, stream);   // zero hist + cnt + bar

  kA_scan<<<dim3(KAB_BLOCKS), dim3(256), 0, stream>>>(
      obj0, cls0, obj1, cls1, obj2, cls2, hist, amax);
  kB_collect<<<dim3(KAB_BLOCKS), dim3(256), 0, stream>>>(
      obj0, cls0, obj1, cls1, obj2, cls2, amax, hist, cnt, cand);
  kT_select_nms<<<dim3(5), dim3(1024), 31296, stream>>>(
      reg0, reg1, reg2, cand, cnt, matg, bar, out);
}